// Round 3
// baseline (503.510 us; speedup 1.0000x reference)
//
#include <hip/hip_runtime.h>
#include <cstdint>
#include <cstddef>

#define NN 30000
#define NE 480000
#define NG 128
#define DIN 128
#define DH 256
#define NC 60
#define CAP 64               // bucket capacity per node (true deg ~ Poisson(16); P(>64) ~ 1e-20)
#define P1MAX (NN * DIN / 4) // 960000: widest job in pre phase

typedef _Float16 f16x8 __attribute__((ext_vector_type(8)));
typedef _Float16 half4_t __attribute__((ext_vector_type(4)));
typedef float f32x4 __attribute__((ext_vector_type(4)));

// async global->LDS, 16B per lane (wave-uniform base + lane*16 dest required)
__device__ __forceinline__ void gload_lds16(const _Float16* g, _Float16* l) {
    __builtin_amdgcn_global_load_lds(
        (const __attribute__((address_space(1))) void*)g,
        (__attribute__((address_space(3))) void*)l, 16, 0, 0);
}

// ---------------- fused pre: bucket edges + x->fp16 + W->fp16 + zero sums ----------------
__global__ __launch_bounds__(256) void k_pre(const int* __restrict__ ei, int* __restrict__ cursor,
        int* __restrict__ csr_src,
        const float* __restrict__ x, _Float16* __restrict__ xh,
        const float* __restrict__ W1, const float* __restrict__ W2, const float* __restrict__ W3,
        _Float16* __restrict__ w1h, _Float16* __restrict__ w2h, _Float16* __restrict__ w3h,
        float* __restrict__ sums) {
    int i = blockIdx.x * 256 + threadIdx.x;
    if (i < NE) {
        int s = ei[i];        // edge_index[0]
        int d = ei[NE + i];   // edge_index[1]
        int slot = atomicAdd(&cursor[d], 1);
        if (slot < CAP) csr_src[d * CAP + slot] = s;
    }
    if (i < P1MAX) {
        float4 v = ((const float4*)x)[i];
        half4_t o;
        o[0] = (_Float16)v.x; o[1] = (_Float16)v.y;
        o[2] = (_Float16)v.z; o[3] = (_Float16)v.w;
        ((half4_t*)xh)[i] = o;
    }
    if (i < DH * DIN) w1h[i] = (_Float16)W1[i];
    if (i < DH * DH) {
        w2h[i] = (_Float16)W2[i];
        w3h[i] = (_Float16)W3[i];
    }
    if (i < NG * DH) sums[i] = 0.f;
}

// ---------------- aggregation: u[v] = sum_e w_e*hin[src_e] + hin[v]/(deg_v+1) ----------------
// XCD-sliced: the 15.4 MB (K=256) gather plane fetched ~8x over in the unsliced version
// (FETCH_SIZE 101 MB, round 2) because random gathers from all XCDs pull the whole plane
// into every per-XCD L2. Here each block owns (node-group, feature-slice) with
// slice = blockIdx % 8: under round-robin block->XCD dispatch, slice s stays on XCD s and
// its hot gather set is NN * (K/8) * 2B = 1.92 MB (K=256) -> fits the 4 MB per-XCD L2.
// Edge list is streamed with nontemporal loads so it doesn't thrash the hot slice.
// One wave = one node-slice; L = lanes per edge (16B chunks), G = 64/L edges per round.
// Butterfly reduce across edge-groups at the end. fp16 in/out, fp32 accumulate.
template<int K>
__global__ __launch_bounds__(256) void k_agg(const _Float16* __restrict__ hin,
        _Float16* __restrict__ tout, const int* __restrict__ cnt,
        const int* __restrict__ csr_src) {
    constexpr int SL = 8;            // feature slices == XCD count
    constexpr int COLS = K / SL;     // halves per slice: 32 (K=256) / 16 (K=128)
    constexpr int L = COLS / 8;      // lanes per edge: 4 / 2
    constexpr int G = 64 / L;        // edges per wave round: 16 / 32
    int bid = blockIdx.x;
    int slice = bid & 7;             // pinned to XCD by dispatch round-robin
    int nb = bid >> 3;
    int node = nb * 4 + (threadIdx.x >> 6);
    int lane = threadIdx.x & 63;
    int sub = lane / L;              // edge slot within the round
    int off = lane % L;              // 16B chunk within the 64B/32B slice
    const _Float16* gbase = hin + slice * COLS + off * 8;
    float acc[8];
    #pragma unroll
    for (int u = 0; u < 8; u++) acc[u] = 0.f;
    int deg = cnt[node];
    float dvd = rsqrtf((float)(deg + 1));
    int c = deg < CAP ? deg : CAP;
    int beg = node * CAP, end = beg + c;
    for (int e = beg; e < end; e += G) {
        int idx = e + sub;
        int s0 = node; float w0 = 0.f;     // idle lanes: weight 0 on a safe (self) row
        if (idx < end) {
            s0 = __builtin_nontemporal_load(&csr_src[idx]);
            w0 = rsqrtf((float)(cnt[s0] + 1)) * dvd;
        }
        f16x8 r0 = *(const f16x8*)(gbase + (size_t)s0 * K);
        #pragma unroll
        for (int u = 0; u < 8; u++) acc[u] = fmaf(w0, (float)r0[u], acc[u]);
    }
    // self loop: weight 1/(deg+1), counted once per slice (sub==0 lanes only)
    {
        float sws = (sub == 0) ? dvd * dvd : 0.f;
        f16x8 rs = *(const f16x8*)(gbase + (size_t)node * K);
        #pragma unroll
        for (int u = 0; u < 8; u++) acc[u] = fmaf(sws, (float)rs[u], acc[u]);
    }
    // butterfly reduce across edge slots (partners share 'off' since L | mask)
    #pragma unroll
    for (int u = 0; u < 8; u++) {
        float v = acc[u];
        #pragma unroll
        for (int m = L; m < 64; m <<= 1) v += __shfl_xor(v, m, 64);
        acc[u] = v;
    }
    if (sub == 0) {
        f16x8 o;
        #pragma unroll
        for (int u = 0; u < 8; u++) o[u] = (_Float16)acc[u];
        *(f16x8*)(tout + (size_t)node * K + slice * COLS + off * 8) = o;
    }
}

// ---------------- fp16 MFMA GEMM: C[M x 256] = relu(A * W^T + bias) ----------------
// BM=64 x BN=64, BK=32, 4 waves, wave tile 32x32 (2x2 of 16x16x32). Single-buffered:
// the round-2 dbuf variant (32 KB LDS) capped residency at 5 blocks/CU and regressed;
// 16 KB keeps 8 blocks/CU (~8 waves/SIMD) and lets TLP hide the staging drain.
// Staging via global_load_lds width=16; LDS stride 32 halves UNPADDED (lane-contiguous
// dest constraint; thread t's 16B chunk lands at t*16 B).
// FUSE_POOL=true (layer 3): epilogue run-sums per graph (batch sorted) -> atomicAdd.
template<int K, bool FUSE_POOL>
__global__ __launch_bounds__(256) void k_gemm(const _Float16* __restrict__ A,
        const _Float16* __restrict__ W, const float* __restrict__ bias,
        _Float16* __restrict__ Cb, const int* __restrict__ batch,
        float* __restrict__ sums) {
    __shared__ __align__(16) _Float16 lsA[64 * 32];
    __shared__ __align__(16) _Float16 lsB[64 * 32];
    int t = threadIdx.x;
    int bm = blockIdx.x * 64;
    int bn = blockIdx.y * 64;
    int lane = t & 63, wv = t >> 6;
    int wm = (wv & 1) * 32;
    int wn = (wv >> 1) * 32;
    int lm = lane & 15, q = lane >> 4;
    int r4 = t >> 2;
    int c4 = t & 3;
    int ra = bm + r4; if (ra >= NN) ra = NN - 1;
    int rb = bn + r4;

    f32x4 acc[2][2];
    #pragma unroll
    for (int i = 0; i < 2; i++)
        #pragma unroll
        for (int j = 0; j < 2; j++) acc[i][j] = (f32x4){0.f, 0.f, 0.f, 0.f};

    for (int k0 = 0; k0 < K; k0 += 32) {
        size_t ko = (size_t)k0 + c4 * 8;
        __syncthreads();  // previous tile fully consumed before LDS overwrite
        // thread t -> LDS half-offset r4*32 + c4*8 == t*8 (lane-contiguous 16B chunks)
        gload_lds16(A + (size_t)ra * K + ko, lsA + t * 8);
        gload_lds16(W + (size_t)rb * K + ko, lsB + t * 8);
        __syncthreads();  // drains vmcnt (compiler inserts) + all lanes staged
        f16x8 bf[2];
        #pragma unroll
        for (int nt = 0; nt < 2; nt++)
            bf[nt] = *(const f16x8*)&lsB[(wn + nt * 16 + lm) * 32 + q * 8];
        #pragma unroll
        for (int mt = 0; mt < 2; mt++) {
            f16x8 af = *(const f16x8*)&lsA[(wm + mt * 16 + lm) * 32 + q * 8];
            #pragma unroll
            for (int nt = 0; nt < 2; nt++)
                acc[mt][nt] = __builtin_amdgcn_mfma_f32_16x16x32_f16(af, bf[nt], acc[mt][nt], 0, 0, 0);
        }
    }
    // epilogue: C/D layout col = lane&15, row = q*4 + r
    if constexpr (!FUSE_POOL) {
        #pragma unroll
        for (int mt = 0; mt < 2; mt++) {
            #pragma unroll
            for (int nt = 0; nt < 2; nt++) {
                int col = bn + wn + nt * 16 + lm;
                float bv = bias[col];
                #pragma unroll
                for (int r = 0; r < 4; r++) {
                    int row = bm + wm + mt * 16 + q * 4 + r;
                    if (row < NN) {
                        float v = fmaxf(acc[mt][nt][r] + bv, 0.f);
                        Cb[(size_t)row * 256 + col] = (_Float16)v;
                    }
                }
            }
        }
    } else {
        // graph ids for this lane's 8 rows (ascending; reused across nt)
        int gid[8];
        #pragma unroll
        for (int mt = 0; mt < 2; mt++)
            #pragma unroll
            for (int r = 0; r < 4; r++) {
                int row = bm + wm + mt * 16 + q * 4 + r;
                gid[mt * 4 + r] = (row < NN) ? batch[row] : -1;
            }
        #pragma unroll
        for (int nt = 0; nt < 2; nt++) {
            int col = bn + wn + nt * 16 + lm;
            float bv = bias[col];
            float runsum = 0.f;
            int curg = -1;
            #pragma unroll
            for (int mt = 0; mt < 2; mt++) {
                #pragma unroll
                for (int r = 0; r < 4; r++) {
                    int g = gid[mt * 4 + r];
                    if (g >= 0) {
                        float v = fmaxf(acc[mt][nt][r] + bv, 0.f);
                        if (g != curg) {
                            if (curg >= 0) atomicAdd(&sums[curg * DH + col], runsum);
                            curg = g;
                            runsum = 0.f;
                        }
                        runsum += v;
                    }
                }
            }
            if (curg >= 0) atomicAdd(&sums[curg * DH + col], runsum);
        }
    }
}

// ---------------- FC: out[G x 60] = (sums[g]/cnt) @ Wfc[60 x 256]^T + bfc ----------------
__global__ __launch_bounds__(64) void k_fc(const float* __restrict__ sums,
        const int* __restrict__ batch, const float* __restrict__ Wfc,
        const float* __restrict__ bfc, float* __restrict__ out) {
    __shared__ float p[DH];
    int g = blockIdx.x;
    int t = threadIdx.x;
    int lo = 0, hi = NN;
    while (lo < hi) { int mid = (lo + hi) >> 1; if (batch[mid] < g) lo = mid + 1; else hi = mid; }
    int start = lo;
    hi = NN;
    while (lo < hi) { int mid = (lo + hi) >> 1; if (batch[mid] < g + 1) lo = mid + 1; else hi = mid; }
    int cnt = lo - start;
    float inv = (cnt > 0) ? 1.f / (float)cnt : 0.f;
    for (int i = t; i < DH; i += 64) p[i] = sums[g * DH + i] * inv;
    __syncthreads();
    if (t < NC) {
        float a = bfc[t];
        for (int k = 0; k < DH; k++) a = fmaf(p[k], Wfc[t * DH + k], a);
        out[g * NC + t] = a;
    }
}

extern "C" void kernel_launch(void* const* d_in, const int* in_sizes, int n_in,
                              void* d_out, int out_size, void* d_ws, size_t ws_size,
                              hipStream_t stream) {
    const float* x     = (const float*)d_in[0];
    const int*   ei    = (const int*)d_in[1];
    const int*   batch = (const int*)d_in[2];
    const float* W1 = (const float*)d_in[3];
    const float* b1 = (const float*)d_in[4];
    const float* W2 = (const float*)d_in[5];
    const float* b2 = (const float*)d_in[6];
    const float* W3 = (const float*)d_in[7];
    const float* b3 = (const float*)d_in[8];
    const float* Wfc = (const float*)d_in[9];
    const float* bfc = (const float*)d_in[10];
    float* out = (float*)d_out;

    char* wp = (char*)d_ws;
    auto alloc = [&](size_t bytes) {
        char* q = wp;
        wp += (bytes + 511) & ~(size_t)511;
        return (void*)q;
    };
    int*   cursor  = (int*)alloc((size_t)NN * 4);               // true in-degree after pre
    int*   csr_src = (int*)alloc((size_t)NN * CAP * 4);         // bucket CSR
    float* sums    = (float*)alloc((size_t)NG * DH * 4);        // zeroed inside k_pre
    _Float16* xh   = (_Float16*)alloc((size_t)NN * DIN * 2);
    _Float16* tb   = (_Float16*)alloc((size_t)NN * DH * 2);
    _Float16* hA   = (_Float16*)alloc((size_t)NN * DH * 2);
    _Float16* hB   = (_Float16*)alloc((size_t)NN * DH * 2);
    _Float16* w1h = (_Float16*)alloc((size_t)DH * DIN * 2);
    _Float16* w2h = (_Float16*)alloc((size_t)DH * DH * 2);
    _Float16* w3h = (_Float16*)alloc((size_t)DH * DH * 2);

    // only cursor must be zero before pre's atomics (120 KB)
    hipMemsetAsync(cursor, 0, (size_t)NN * 4, stream);

    k_pre<<<(P1MAX + 255) / 256, 256, 0, stream>>>(ei, cursor, csr_src, x, xh,
                                                   W1, W2, W3, w1h, w2h, w3h, sums);

    dim3 gg((NN + 63) / 64, 4);
    int gagg = (NN / 4) * 8;   // (node-groups) x (8 feature slices), slice = bid % 8
    // h_l = relu((A.h_{l-1}) W^T + b)  [linearity reorder]
    k_agg<128><<<gagg, 256, 0, stream>>>(xh, tb, cursor, csr_src);
    k_gemm<128, false><<<gg, 256, 0, stream>>>(tb, w1h, b1, hA, nullptr, nullptr);
    k_agg<256><<<gagg, 256, 0, stream>>>(hA, tb, cursor, csr_src);
    k_gemm<256, false><<<gg, 256, 0, stream>>>(tb, w2h, b2, hB, nullptr, nullptr);
    k_agg<256><<<gagg, 256, 0, stream>>>(hB, tb, cursor, csr_src);
    k_gemm<256, true><<<gg, 256, 0, stream>>>(tb, w3h, b3, nullptr, batch, sums);  // + pool

    k_fc<<<NG, 64, 0, stream>>>(sums, batch, Wfc, bfc, out);
}

// Round 4
// 276.574 us; speedup vs baseline: 1.8205x; 1.8205x over previous
//
#include <hip/hip_runtime.h>
#include <cstdint>
#include <cstddef>

#define NN 30000
#define NE 480000
#define NG 128
#define DIN 128
#define DH 256
#define NC 60
#define CAP 64               // bucket capacity per node (true deg ~ Poisson(16); P(>64) ~ 1e-20)
#define P1MAX (NN * DIN / 4) // 960000: widest job in pre phase

typedef _Float16 f16x8 __attribute__((ext_vector_type(8)));
typedef _Float16 half4_t __attribute__((ext_vector_type(4)));
typedef float f32x4 __attribute__((ext_vector_type(4)));

// async global->LDS, 16B per lane (wave-uniform base + lane*16 dest required)
__device__ __forceinline__ void gload_lds16(const _Float16* g, _Float16* l) {
    __builtin_amdgcn_global_load_lds(
        (const __attribute__((address_space(1))) void*)g,
        (__attribute__((address_space(3))) void*)l, 16, 0, 0);
}

// ---------------- fused pre: bucket edges + x->fp16 + W->fp16 + zero sums ----------------
__global__ __launch_bounds__(256) void k_pre(const int* __restrict__ ei, int* __restrict__ cursor,
        int* __restrict__ csr_src,
        const float* __restrict__ x, _Float16* __restrict__ xh,
        const float* __restrict__ W1, const float* __restrict__ W2, const float* __restrict__ W3,
        _Float16* __restrict__ w1h, _Float16* __restrict__ w2h, _Float16* __restrict__ w3h,
        float* __restrict__ sums) {
    int i = blockIdx.x * 256 + threadIdx.x;
    if (i < NE) {
        int s = ei[i];        // edge_index[0]
        int d = ei[NE + i];   // edge_index[1]
        int slot = atomicAdd(&cursor[d], 1);
        if (slot < CAP) csr_src[d * CAP + slot] = s;
    }
    if (i < P1MAX) {
        float4 v = ((const float4*)x)[i];
        half4_t o;
        o[0] = (_Float16)v.x; o[1] = (_Float16)v.y;
        o[2] = (_Float16)v.z; o[3] = (_Float16)v.w;
        ((half4_t*)xh)[i] = o;
    }
    if (i < DH * DIN) w1h[i] = (_Float16)W1[i];
    if (i < DH * DH) {
        w2h[i] = (_Float16)W2[i];
        w3h[i] = (_Float16)W3[i];
    }
    if (i < NG * DH) sums[i] = 0.f;
}

// ---------------- edge weights: sw[e] = (src, rsqrt(deg_s+1)*rsqrt(deg_d+1)) ----------------
// Done ONCE after k_pre, so the 3 aggregation passes never touch cnt[] or rsqrt in their
// inner loops (round-3 lesson: duplicated per-edge metadata dominated). One wave per node,
// lane = bucket slot (CAP == 64 == wave width).
__global__ __launch_bounds__(256) void k_wt(const int* __restrict__ cnt,
        const int* __restrict__ csr_src, int2* __restrict__ sw) {
    int node = blockIdx.x * 4 + (threadIdx.x >> 6);
    int lane = threadIdx.x & 63;
    int deg = cnt[node];
    float dvd = rsqrtf((float)(deg + 1));
    int c = deg < CAP ? deg : CAP;
    if (lane < c) {
        int s = csr_src[node * CAP + lane];
        float w = rsqrtf((float)(cnt[s] + 1)) * dvd;
        sw[node * CAP + lane] = make_int2(s, __float_as_int(w));
    }
}

// ---------------- aggregation: u[v] = sum_e w_e*hin[src_e] + hin[v]/(deg_v+1) ----------------
// One wave per node. 16B/lane row gathers: wave splits into G = 64/(K/8) edge slots.
// Inner loop per edge: one sequential 8B (src,w) load + one 16B gather + 8 cvt/fma.
// Tier 16 keeps 8 (K=256) / 4 (K=128) gathers in flight; tail = <=2 predicated 8-edge
// rounds (4 / 2 gathers in flight) instead of latency-serial G-steps.
// Butterfly reduce across edge slots at the end. fp16 plane in/out, fp32 accumulate.
template<int K>
__global__ __launch_bounds__(256) void k_agg(const _Float16* __restrict__ hin,
        _Float16* __restrict__ tout, const int* __restrict__ cnt,
        const int2* __restrict__ sw) {
    constexpr int L = K / 8;   // lanes per row (16B chunks per row)
    constexpr int G = 64 / L;  // edges per wave round (2 for K=256, 4 for K=128)
    constexpr int B16 = 16 / G;
    constexpr int B8 = 8 / G;
    int node = blockIdx.x * 4 + (threadIdx.x >> 6);
    int lane = threadIdx.x & 63;
    int sub = lane / L;        // edge slot within the round
    int off = lane % L;        // 8-half chunk index within the row
    const _Float16* gbase = hin + off * 8;
    float acc[8];
    #pragma unroll
    for (int u = 0; u < 8; u++) acc[u] = 0.f;
    int deg = cnt[node];
    float dvd = rsqrtf((float)(deg + 1));
    int c = deg < CAP ? deg : CAP;
    int beg = node * CAP, end = beg + c;
    int e = beg;
    // tier 16: covers a whole typical (deg~16) node in one batch
    for (; e + 16 <= end; e += 16) {
        long long sv[B16]; f16x8 r[B16];
        #pragma unroll
        for (int j = 0; j < B16; j++)
            sv[j] = __builtin_nontemporal_load((const long long*)(sw + e + j * G + sub));
        #pragma unroll
        for (int j = 0; j < B16; j++)
            r[j] = *(const f16x8*)(gbase + (size_t)(int)sv[j] * K);
        #pragma unroll
        for (int j = 0; j < B16; j++) {
            float w = __int_as_float((int)(sv[j] >> 32));
            #pragma unroll
            for (int u = 0; u < 8; u++) acc[u] = fmaf(w, (float)r[j][u], acc[u]);
        }
    }
    // predicated 8-edge rounds (<=2): idle lanes get weight 0 on a safe (self) row
    for (; e < end; e += 8) {
        int s[B8]; float w[B8]; f16x8 r[B8];
        #pragma unroll
        for (int j = 0; j < B8; j++) {
            int idx = e + j * G + sub;
            if (idx < end) {
                long long vv = __builtin_nontemporal_load((const long long*)(sw + idx));
                s[j] = (int)vv; w[j] = __int_as_float((int)(vv >> 32));
            } else { s[j] = node; w[j] = 0.f; }
        }
        #pragma unroll
        for (int j = 0; j < B8; j++)
            r[j] = *(const f16x8*)(gbase + (size_t)s[j] * K);
        #pragma unroll
        for (int j = 0; j < B8; j++)
            #pragma unroll
            for (int u = 0; u < 8; u++) acc[u] = fmaf(w[j], (float)r[j][u], acc[u]);
    }
    // self loop: weight 1/(deg+1), counted once (only sub==0 lanes add it)
    {
        float sws = (sub == 0) ? dvd * dvd : 0.f;
        f16x8 rs = *(const f16x8*)(gbase + (size_t)node * K);
        #pragma unroll
        for (int u = 0; u < 8; u++) acc[u] = fmaf(sws, (float)rs[u], acc[u]);
    }
    // butterfly reduce across edge slots (partners share 'off' since L | mask)
    #pragma unroll
    for (int u = 0; u < 8; u++) {
        float v = acc[u];
        #pragma unroll
        for (int m = L; m < 64; m <<= 1) v += __shfl_xor(v, m, 64);
        acc[u] = v;
    }
    if (sub == 0) {
        f16x8 o;
        #pragma unroll
        for (int u = 0; u < 8; u++) o[u] = (_Float16)acc[u];
        *(f16x8*)(tout + (size_t)node * K + off * 8) = o;
    }
}

// ---------------- fp16 MFMA GEMM: C[M x 256] = relu(A * W^T + bias) ----------------
// BM=64 x BN=64, BK=32, 4 waves, wave tile 32x32 (2x2 of 16x16x32). Single-buffered:
// the round-2 dbuf variant (32 KB LDS) capped residency at 5 blocks/CU and regressed;
// 8 KB LDS keeps 8 blocks/CU (~8 waves/SIMD) and TLP hides the staging drain.
// Staging via global_load_lds width=16; LDS stride 32 halves UNPADDED (lane-contiguous
// dest constraint; thread t's 16B chunk lands at t*16 B).
// FUSE_POOL=true (layer 3): epilogue run-sums per graph (batch sorted) -> atomicAdd.
template<int K, bool FUSE_POOL>
__global__ __launch_bounds__(256) void k_gemm(const _Float16* __restrict__ A,
        const _Float16* __restrict__ W, const float* __restrict__ bias,
        _Float16* __restrict__ Cb, const int* __restrict__ batch,
        float* __restrict__ sums) {
    __shared__ __align__(16) _Float16 lsA[64 * 32];
    __shared__ __align__(16) _Float16 lsB[64 * 32];
    int t = threadIdx.x;
    int bm = blockIdx.x * 64;
    int bn = blockIdx.y * 64;
    int lane = t & 63, wv = t >> 6;
    int wm = (wv & 1) * 32;
    int wn = (wv >> 1) * 32;
    int lm = lane & 15, q = lane >> 4;
    int r4 = t >> 2;
    int c4 = t & 3;
    int ra = bm + r4; if (ra >= NN) ra = NN - 1;
    int rb = bn + r4;

    f32x4 acc[2][2];
    #pragma unroll
    for (int i = 0; i < 2; i++)
        #pragma unroll
        for (int j = 0; j < 2; j++) acc[i][j] = (f32x4){0.f, 0.f, 0.f, 0.f};

    for (int k0 = 0; k0 < K; k0 += 32) {
        size_t ko = (size_t)k0 + c4 * 8;
        __syncthreads();  // previous tile fully consumed before LDS overwrite
        // thread t -> LDS half-offset r4*32 + c4*8 == t*8 (lane-contiguous 16B chunks)
        gload_lds16(A + (size_t)ra * K + ko, lsA + t * 8);
        gload_lds16(W + (size_t)rb * K + ko, lsB + t * 8);
        __syncthreads();  // drains vmcnt (compiler inserts) + all lanes staged
        f16x8 bf[2];
        #pragma unroll
        for (int nt = 0; nt < 2; nt++)
            bf[nt] = *(const f16x8*)&lsB[(wn + nt * 16 + lm) * 32 + q * 8];
        #pragma unroll
        for (int mt = 0; mt < 2; mt++) {
            f16x8 af = *(const f16x8*)&lsA[(wm + mt * 16 + lm) * 32 + q * 8];
            #pragma unroll
            for (int nt = 0; nt < 2; nt++)
                acc[mt][nt] = __builtin_amdgcn_mfma_f32_16x16x32_f16(af, bf[nt], acc[mt][nt], 0, 0, 0);
        }
    }
    // epilogue: C/D layout col = lane&15, row = q*4 + r
    if constexpr (!FUSE_POOL) {
        #pragma unroll
        for (int mt = 0; mt < 2; mt++) {
            #pragma unroll
            for (int nt = 0; nt < 2; nt++) {
                int col = bn + wn + nt * 16 + lm;
                float bv = bias[col];
                #pragma unroll
                for (int r = 0; r < 4; r++) {
                    int row = bm + wm + mt * 16 + q * 4 + r;
                    if (row < NN) {
                        float v = fmaxf(acc[mt][nt][r] + bv, 0.f);
                        Cb[(size_t)row * 256 + col] = (_Float16)v;
                    }
                }
            }
        }
    } else {
        // graph ids for this lane's 8 rows (ascending; reused across nt)
        int gid[8];
        #pragma unroll
        for (int mt = 0; mt < 2; mt++)
            #pragma unroll
            for (int r = 0; r < 4; r++) {
                int row = bm + wm + mt * 16 + q * 4 + r;
                gid[mt * 4 + r] = (row < NN) ? batch[row] : -1;
            }
        #pragma unroll
        for (int nt = 0; nt < 2; nt++) {
            int col = bn + wn + nt * 16 + lm;
            float bv = bias[col];
            float runsum = 0.f;
            int curg = -1;
            #pragma unroll
            for (int mt = 0; mt < 2; mt++) {
                #pragma unroll
                for (int r = 0; r < 4; r++) {
                    int g = gid[mt * 4 + r];
                    if (g >= 0) {
                        float v = fmaxf(acc[mt][nt][r] + bv, 0.f);
                        if (g != curg) {
                            if (curg >= 0) atomicAdd(&sums[curg * DH + col], runsum);
                            curg = g;
                            runsum = 0.f;
                        }
                        runsum += v;
                    }
                }
            }
            if (curg >= 0) atomicAdd(&sums[curg * DH + col], runsum);
        }
    }
}

// ---------------- FC: out[G x 60] = (sums[g]/cnt) @ Wfc[60 x 256]^T + bfc ----------------
__global__ __launch_bounds__(64) void k_fc(const float* __restrict__ sums,
        const int* __restrict__ batch, const float* __restrict__ Wfc,
        const float* __restrict__ bfc, float* __restrict__ out) {
    __shared__ float p[DH];
    int g = blockIdx.x;
    int t = threadIdx.x;
    int lo = 0, hi = NN;
    while (lo < hi) { int mid = (lo + hi) >> 1; if (batch[mid] < g) lo = mid + 1; else hi = mid; }
    int start = lo;
    hi = NN;
    while (lo < hi) { int mid = (lo + hi) >> 1; if (batch[mid] < g + 1) lo = mid + 1; else hi = mid; }
    int cnt = lo - start;
    float inv = (cnt > 0) ? 1.f / (float)cnt : 0.f;
    for (int i = t; i < DH; i += 64) p[i] = sums[g * DH + i] * inv;
    __syncthreads();
    if (t < NC) {
        float a = bfc[t];
        for (int k = 0; k < DH; k++) a = fmaf(p[k], Wfc[t * DH + k], a);
        out[g * NC + t] = a;
    }
}

extern "C" void kernel_launch(void* const* d_in, const int* in_sizes, int n_in,
                              void* d_out, int out_size, void* d_ws, size_t ws_size,
                              hipStream_t stream) {
    const float* x     = (const float*)d_in[0];
    const int*   ei    = (const int*)d_in[1];
    const int*   batch = (const int*)d_in[2];
    const float* W1 = (const float*)d_in[3];
    const float* b1 = (const float*)d_in[4];
    const float* W2 = (const float*)d_in[5];
    const float* b2 = (const float*)d_in[6];
    const float* W3 = (const float*)d_in[7];
    const float* b3 = (const float*)d_in[8];
    const float* Wfc = (const float*)d_in[9];
    const float* bfc = (const float*)d_in[10];
    float* out = (float*)d_out;

    char* wp = (char*)d_ws;
    auto alloc = [&](size_t bytes) {
        char* q = wp;
        wp += (bytes + 511) & ~(size_t)511;
        return (void*)q;
    };
    int*   cursor  = (int*)alloc((size_t)NN * 4);               // true in-degree after pre
    int*   csr_src = (int*)alloc((size_t)NN * CAP * 4);         // bucket CSR
    int2*  sw      = (int2*)alloc((size_t)NN * CAP * 8);        // per-edge (src, weight)
    float* sums    = (float*)alloc((size_t)NG * DH * 4);        // zeroed inside k_pre
    _Float16* xh   = (_Float16*)alloc((size_t)NN * DIN * 2);
    _Float16* tb   = (_Float16*)alloc((size_t)NN * DH * 2);
    _Float16* hA   = (_Float16*)alloc((size_t)NN * DH * 2);
    _Float16* hB   = (_Float16*)alloc((size_t)NN * DH * 2);
    _Float16* w1h = (_Float16*)alloc((size_t)DH * DIN * 2);
    _Float16* w2h = (_Float16*)alloc((size_t)DH * DH * 2);
    _Float16* w3h = (_Float16*)alloc((size_t)DH * DH * 2);

    // only cursor must be zero before pre's atomics (120 KB)
    hipMemsetAsync(cursor, 0, (size_t)NN * 4, stream);

    k_pre<<<(P1MAX + 255) / 256, 256, 0, stream>>>(ei, cursor, csr_src, x, xh,
                                                   W1, W2, W3, w1h, w2h, w3h, sums);
    k_wt<<<NN / 4, 256, 0, stream>>>(cursor, csr_src, sw);

    dim3 gg((NN + 63) / 64, 4);
    // h_l = relu((A.h_{l-1}) W^T + b)  [linearity reorder]
    k_agg<128><<<NN / 4, 256, 0, stream>>>(xh, tb, cursor, sw);
    k_gemm<128, false><<<gg, 256, 0, stream>>>(tb, w1h, b1, hA, nullptr, nullptr);
    k_agg<256><<<NN / 4, 256, 0, stream>>>(hA, tb, cursor, sw);
    k_gemm<256, false><<<gg, 256, 0, stream>>>(tb, w2h, b2, hB, nullptr, nullptr);
    k_agg<256><<<NN / 4, 256, 0, stream>>>(hB, tb, cursor, sw);
    k_gemm<256, true><<<gg, 256, 0, stream>>>(tb, w3h, b3, nullptr, batch, sums);  // + pool

    k_fc<<<NG, 64, 0, stream>>>(sums, batch, Wfc, bfc, out);
}